// Round 11
// baseline (563.527 us; speedup 1.0000x reference)
//
#include <hip/hip_runtime.h>
#include <hip/hip_bf16.h>

// Problem constants
#define Bn 16
#define Sn 16
#define Ln 64
#define En 512
#define Hn 512
#define Nn 512   // B*2*S packed batch
#define G4 2048  // 4*H

typedef __bf16 bf16x8 __attribute__((ext_vector_type(8)));
typedef float f32x4 __attribute__((ext_vector_type(4)));
typedef unsigned short u16x8 __attribute__((ext_vector_type(8)));
typedef unsigned short u16x4 __attribute__((ext_vector_type(4)));

__device__ __forceinline__ unsigned short f2bf(float f) {
    union { float f; unsigned u; } v; v.f = f;
    unsigned r = v.u + 0x7FFFu + ((v.u >> 16) & 1u);   // RNE
    return (unsigned short)(r >> 16);
}
__device__ __forceinline__ float bf2f(unsigned short u) {
    union { unsigned u; float f; } v; v.u = ((unsigned)u) << 16;
    return v.f;
}
__device__ __forceinline__ float sigmf(float x) {
    return 1.0f / (1.0f + __expf(-x));
}
__device__ __forceinline__ float tanh_fast(float x) {
    x = fminf(fmaxf(x, -15.0f), 15.0f);
    float e = __expf(2.0f * x);
    return (e - 1.0f) / (e + 1.0f);
}

// ---------------------------------------------------------------------------
// ws layout (bytes).  h LINEAR [n][k].
// ---------------------------------------------------------------------------
#define WS_WIHB  0            // Wih bf16 [gcol 2048][k 512], chunk^(gcol&7) swizzle  2MB
#define WS_WHH   2097152      // Whh image [utH 64][col 32][k 512], chunk^(col&7)     2MB
#define WS_BSUM  4194304      // fp32 2048
#define WS_HA    4202496      // h bf16 [n 512][k 512] linear   512KB
#define WS_HB    4726784      // 512KB
#define WS_C     5251072      // fp32 [n][u] 1MB
#define WS_FEAT  6299648      // 128KB
#define WS_Z1    6430720      // 16KB
#define WS_XG    6447104      // Xg bf16 [m 32768][ut 32][u15 16][gate 4]  134MB

// prep_w work items
#define WI_CH 131072
#define WH_CH 131072
#define HZ 32768
#define CZ 65536
#define PREPW_TOTAL (WI_CH + WH_CH + 2048 + HZ + CZ)

__global__ __launch_bounds__(256) void prep_w(
    const float* __restrict__ Wih_f, const float* __restrict__ Whh_f,
    const float* __restrict__ bih, const float* __restrict__ bhh,
    unsigned short* __restrict__ Wihb, unsigned short* __restrict__ WhhImg,
    float* __restrict__ bsum, unsigned short* __restrict__ hA,
    float* __restrict__ c0) {
    int i = blockIdx.x * 256 + threadIdx.x;
    if (i < WI_CH) {
        int gcol = i >> 6, ch = i & 63;
        const float* s = Wih_f + (size_t)gcol * 512 + ch * 8;
        u16x8 w;
#pragma unroll
        for (int j = 0; j < 8; ++j) w[j] = f2bf(s[j]);
        *(u16x8*)(Wihb + (size_t)gcol * 512 + (ch ^ (gcol & 7)) * 8) = w;
    } else if (i < WI_CH + WH_CH) {
        int j = i - WI_CH;
        int g4row = j >> 6, ch = j & 63;
        int gate = g4row >> 9, unit = g4row & 511;
        int utH = unit >> 3, col = gate * 8 + (unit & 7);
        const float* s = Whh_f + (size_t)g4row * 512 + ch * 8;
        u16x8 w;
#pragma unroll
        for (int k = 0; k < 8; ++k) w[k] = f2bf(s[k]);
        *(u16x8*)(WhhImg + utH * 16384 + col * 512 + (ch ^ (col & 7)) * 8) = w;
    } else if (i < WI_CH + WH_CH + 2048) {
        int j = i - (WI_CH + WH_CH);
        bsum[j] = bih[j] + bhh[j];
    } else if (i < WI_CH + WH_CH + 2048 + HZ) {
        int j = i - (WI_CH + WH_CH + 2048);
        u16x8 z = {0, 0, 0, 0, 0, 0, 0, 0};
        *(u16x8*)(hA + j * 8) = z;
    } else if (i < PREPW_TOTAL) {
        int j = i - (WI_CH + WH_CH + 2048 + HZ);
        f32x4 z = {0.f, 0.f, 0.f, 0.f};
        *(f32x4*)(c0 + j * 4) = z;
    }
}

// ---------------------------------------------------------------------------
// Xg = x(bf16-cvt) @ Wih^T : M=32768 (m=t*512+n), N=2048, K=512.
// 128x128 tile, BK=64; A staged from fp32 x with in-register cvt, swizzle
// applied at LDS write; B from pre-swizzled Wihb, linear write.
// XCD-chunked block map; epilogue writes gate-packed [m][ut][u15][gate].
// ---------------------------------------------------------------------------
__global__ __launch_bounds__(256) void xg_gemm(
    const float* __restrict__ xf, const float* __restrict__ xa,
    const unsigned short* __restrict__ Wihb,
    unsigned short* __restrict__ Xg) {
    __shared__ __align__(16) unsigned short As[2][8192];  // [128 rows][64 k]
    __shared__ __align__(16) unsigned short Bs[2][8192];
    const int tid = threadIdx.x;
    const int p = blockIdx.x;
    const int L = (p & 7) * 512 + (p >> 3);   // bijective XCD-chunked map
    const int bx = L >> 4, by = L & 15;
    const size_t m0 = (size_t)bx * 128;
    const int n0 = by * 128;
    const int wv = tid >> 6, lane = tid & 63;
    const int l15 = lane & 15, sel = lane >> 4;
    const int wm = wv >> 1, wn = wv & 1;

    const int srow = tid >> 3;        // 0..31, + r*32
    const int sseg = tid & 7;         // 8 u16 each

    // A source rows (x fp32) and swizzled LDS write offsets
    const float* xrowp[4];
    int awofs[4];
#pragma unroll
    for (int r = 0; r < 4; ++r) {
        const int m = (int)m0 + r * 32 + srow;
        const int tt = m >> 9, n = m & 511;
        const int bb = n >> 5, rr = n & 31;
        xrowp[r] = ((rr < Sn)
            ? xf + ((size_t)(bb * Sn + rr) * Ln + tt) * En
            : xa + ((size_t)(bb * Sn + (rr - Sn)) * Ln + tt) * En) + sseg * 8;
        awofs[r] = (r * 32 + srow) * 128 + ((sseg ^ (srow & 7)) * 16);
    }
    const unsigned short* bsrc = Wihb + (size_t)(n0 + srow) * 512 + sseg * 8;

    f32x4 acc[4][4];
#pragma unroll
    for (int i = 0; i < 4; ++i)
#pragma unroll
        for (int j = 0; j < 4; ++j) acc[i][j] = (f32x4){0.f, 0.f, 0.f, 0.f};

    float4 av[4][2];
    u16x8 br[4];
#pragma unroll
    for (int r = 0; r < 4; ++r) {
        av[r][0] = *(const float4*)(xrowp[r]);
        av[r][1] = *(const float4*)(xrowp[r] + 4);
        br[r] = *(const u16x8*)(bsrc + (size_t)r * 32 * 512);
    }

#pragma unroll 1
    for (int it = 0; it < 8; ++it) {
        unsigned short* Ac = As[it & 1];
        unsigned short* Bc = Bs[it & 1];
#pragma unroll
        for (int r = 0; r < 4; ++r) {
            u16x8 w;
            w[0] = (unsigned short)__bfloat16_as_ushort((__hip_bfloat16)av[r][0].x);
            w[1] = (unsigned short)__bfloat16_as_ushort((__hip_bfloat16)av[r][0].y);
            w[2] = (unsigned short)__bfloat16_as_ushort((__hip_bfloat16)av[r][0].z);
            w[3] = (unsigned short)__bfloat16_as_ushort((__hip_bfloat16)av[r][0].w);
            w[4] = (unsigned short)__bfloat16_as_ushort((__hip_bfloat16)av[r][1].x);
            w[5] = (unsigned short)__bfloat16_as_ushort((__hip_bfloat16)av[r][1].y);
            w[6] = (unsigned short)__bfloat16_as_ushort((__hip_bfloat16)av[r][1].z);
            w[7] = (unsigned short)__bfloat16_as_ushort((__hip_bfloat16)av[r][1].w);
            *(u16x8*)((char*)Ac + awofs[r]) = w;
            *(u16x8*)((char*)Bc + r * 4096 + tid * 16) = br[r];
        }
        if (it < 7) {
#pragma unroll
            for (int r = 0; r < 4; ++r) {
                av[r][0] = *(const float4*)(xrowp[r] + (it + 1) * 64);
                av[r][1] = *(const float4*)(xrowp[r] + (it + 1) * 64 + 4);
                br[r] = *(const u16x8*)(bsrc + (size_t)r * 32 * 512 + (it + 1) * 64);
            }
        }
        __syncthreads();
#pragma unroll
        for (int ks = 0; ks < 2; ++ks) {
            bf16x8 a[4], b[4];
#pragma unroll
            for (int i = 0; i < 4; ++i) {
                const int arow = wm * 64 + i * 16 + l15;
                a[i] = *(const bf16x8*)(Ac + arow * 64 + (((ks * 4 + sel) ^ (arow & 7)) * 8));
                const int brow = wn * 64 + i * 16 + l15;
                b[i] = *(const bf16x8*)(Bc + brow * 64 + (((ks * 4 + sel) ^ (brow & 7)) * 8));
            }
#pragma unroll
            for (int i = 0; i < 4; ++i)
#pragma unroll
                for (int j = 0; j < 4; ++j)
                    acc[i][j] = __builtin_amdgcn_mfma_f32_16x16x32_bf16(a[i], b[j], acc[i][j], 0, 0, 0);
        }
        __syncthreads();
    }
    // epilogue: gate-packed store. gate = by>>2, ut = (by&3)*8 + wn*4 + j.
    const int gate = by >> 2;
#pragma unroll
    for (int i = 0; i < 4; ++i)
#pragma unroll
        for (int j = 0; j < 4; ++j) {
            const int ut = (by & 3) * 8 + wn * 4 + j;
#pragma unroll
            for (int q = 0; q < 4; ++q) {
                const size_t m = m0 + wm * 64 + i * 16 + sel * 4 + q;
                Xg[m * 2048 + ut * 64 + l15 * 4 + gate] = f2bf(acc[i][j][q]);
            }
        }
}

// ---------------------------------------------------------------------------
// LSTM step v4: grid 512 (nt8 x utH64) x 256 thr (4 waves), 2 WGs/CU.
// WG = 64 rows x 32 gate-major cols (8 units x 4 gates, col = gate*8+u7).
// Wave w owns rows w*16..+15; lane pair (l15, l15^8) holds gates {hi,hi+2}
// of unit u7 -> full cell via 8 shfl_xor(8), no dump, ONE barrier.
// B (32KB Whh slice) single-staged in LDS; A (h) direct global->reg.
// ---------------------------------------------------------------------------
__global__ __launch_bounds__(256) void lstm_step(
    const unsigned short* __restrict__ WhhImg,
    const unsigned short* __restrict__ Xg, const float* __restrict__ bsum,
    const unsigned short* __restrict__ h_in, unsigned short* __restrict__ h_out,
    float* __restrict__ c, int t) {
    __shared__ __align__(16) unsigned short Bsl[16384];   // 32KB

    const int tid = threadIdx.x, bid = blockIdx.x;
    const int nt = bid & 7, utH = bid >> 3;   // nt == XCD under round-robin
    const int n0 = nt * 64;
    const int w = tid >> 6, lane = tid & 63;
    const int l15 = lane & 15, sel = lane >> 4;
    const int hi = l15 >> 3;                  // gate-half
    const int u7 = l15 & 7;
    const int uglob = utH * 8 + u7;
    const int qbase = hi * 2;
    const int r0 = w * 16 + sel * 4 + qbase;  // first of my 2 rows (rel n0)

    // ---- early loads: Xg (gate-packed), c, biases for my 2 cells
    u16x4 xv[2];
    float cv[2];
#pragma unroll
    for (int e = 0; e < 2; ++e) {
        const size_t n = n0 + r0 + e;
        xv[e] = *(const u16x4*)(Xg + ((size_t)t * 512 + n) * 2048 +
                                (uglob >> 4) * 64 + (uglob & 15) * 4);
        cv[e] = c[n * 512 + uglob];
    }
    const float bI = bsum[uglob];
    const float bF = bsum[512 + uglob];
    const float bG = bsum[1024 + uglob];
    const float bO = bsum[1536 + uglob];

    // ---- stage B: 32KB linear copy (8 x 16B per thread)
    {
        const unsigned short* src = WhhImg + utH * 16384;
#pragma unroll
        for (int r = 0; r < 8; ++r)
            *(u16x8*)((char*)Bsl + (r * 256 + tid) * 16) =
                *(const u16x8*)(src + (r * 256 + tid) * 8);
    }
    __syncthreads();

    // ---- K-loop: 16 kb fully unrolled, A direct from global (L2-hot)
    const unsigned short* hrow = h_in + (size_t)(n0 + w * 16 + l15) * 512;
    f32x4 acc0 = (f32x4){0.f, 0.f, 0.f, 0.f};
    f32x4 acc1 = (f32x4){0.f, 0.f, 0.f, 0.f};
#pragma unroll
    for (int kb = 0; kb < 16; ++kb) {
        bf16x8 a = *(const bf16x8*)(hrow + kb * 32 + sel * 8);
        {
            const int col = l15;                         // gates {0,1}
            bf16x8 b = *(const bf16x8*)((const char*)Bsl + col * 1024 +
                                        (((kb * 4 + sel) ^ (col & 7)) * 16));
            acc0 = __builtin_amdgcn_mfma_f32_16x16x32_bf16(a, b, acc0, 0, 0, 0);
        }
        {
            const int col = 16 + l15;                    // gates {2,3}
            bf16x8 b = *(const bf16x8*)((const char*)Bsl + col * 1024 +
                                        (((kb * 4 + sel) ^ (col & 7)) * 16));
            acc1 = __builtin_amdgcn_mfma_f32_16x16x32_bf16(a, b, acc1, 0, 0, 0);
        }
    }

    // ---- gate exchange within lane pair (l15 ^ 8)
    float p0[4], p1[4];
#pragma unroll
    for (int q = 0; q < 4; ++q) {
        p0[q] = __shfl_xor(acc0[q], 8);
        p1[q] = __shfl_xor(acc1[q], 8);
    }

    // ---- lane-local cell for my 2 rows
#pragma unroll
    for (int e = 0; e < 2; ++e) {
        const int q = qbase + e;
        const float gI = (hi ? p0[q] : acc0[q]) + bf2f(xv[e][0]) + bI;
        const float gF = (hi ? acc0[q] : p0[q]) + bf2f(xv[e][1]) + bF;
        const float gG = (hi ? p1[q] : acc1[q]) + bf2f(xv[e][2]) + bG;
        const float gO = (hi ? acc1[q] : p1[q]) + bf2f(xv[e][3]) + bO;
        const float I = sigmf(gI), F = sigmf(gF);
        const float G = tanh_fast(gG), O = sigmf(gO);
        const float cn = F * cv[e] + I * G;
        const size_t n = n0 + r0 + e;
        c[n * 512 + uglob] = cn;
        h_out[n * 512 + uglob] = f2bf(O * tanh_fast(cn));
    }
}

// ---------------------------------------------------------------------------
// Head: pool (h linear), fc1, fc2.
// ---------------------------------------------------------------------------
__global__ __launch_bounds__(256) void pool_kernel(
    const unsigned short* __restrict__ hfin, float* __restrict__ feat) {
    const int blk = blockIdx.x;
    const int b = blk >> 1, side = blk & 1;
    const int tid = threadIdx.x;
    for (int u = tid; u < Hn; u += 256) {
        float s = 0.0f, m = -1e30f;
#pragma unroll
        for (int ss = 0; ss < Sn; ++ss) {
            const int n = b * 32 + side * 16 + ss;
            float v = bf2f(hfin[(size_t)n * 512 + u]);
            s += v;
            m = fmaxf(m, v);
        }
        feat[b * 2048 + side * 1024 + u] = s * (1.0f / 16.0f);
        feat[b * 2048 + side * 1024 + 512 + u] = m;
    }
}

__global__ __launch_bounds__(256) void fc1_kernel(
    const float* __restrict__ feat, const float* __restrict__ fc1w,
    const float* __restrict__ fc1b, float* __restrict__ z1) {
    __shared__ float fs[2048];
    __shared__ float red[256];
    const int b = blockIdx.x >> 4, oc = blockIdx.x & 15;
    const int tid = threadIdx.x;
    for (int k = tid; k < 2048; k += 256) fs[k] = feat[b * 2048 + k];
    __syncthreads();
    const int o = oc * 16 + (tid & 15);
    const int ks = (tid >> 4) * 128;
    const float4* w4 = (const float4*)(fc1w + (size_t)o * 2048 + ks);
    const float* fr = fs + ks;
    float p = 0.0f;
#pragma unroll 8
    for (int k = 0; k < 32; ++k) {
        float4 w = w4[k];
        p += fr[k * 4] * w.x + fr[k * 4 + 1] * w.y +
             fr[k * 4 + 2] * w.z + fr[k * 4 + 3] * w.w;
    }
    red[(tid & 15) * 16 + (tid >> 4)] = p;
    __syncthreads();
    if (tid < 16) {
        float z = fc1b[oc * 16 + tid];
#pragma unroll
        for (int j = 0; j < 16; ++j) z += red[tid * 16 + j];
        z1[b * 256 + oc * 16 + tid] = z;
    }
}

__global__ __launch_bounds__(256) void fc2_kernel(
    const float* __restrict__ z1, const float* __restrict__ fc2w,
    const float* __restrict__ fc2b, float* __restrict__ out) {
    __shared__ float sh[256];
    const int b = blockIdx.x, tid = threadIdx.x;
    sh[tid] = z1[b * 256 + tid] * fc2w[tid];
    __syncthreads();
    for (int s = 128; s > 0; s >>= 1) {
        if (tid < s) sh[tid] += sh[tid + s];
        __syncthreads();
    }
    if (tid == 0) out[b] = sigmf(sh[0] + fc2b[0]);
}

// ---------------------------------------------------------------------------
extern "C" void kernel_launch(void* const* d_in, const int* in_sizes, int n_in,
                              void* d_out, int out_size, void* d_ws, size_t ws_size,
                              hipStream_t stream) {
    const float* xf    = (const float*)d_in[0];
    const float* xa    = (const float*)d_in[1];
    const float* Wih_f = (const float*)d_in[2];
    const float* Whh_f = (const float*)d_in[3];
    const float* bih   = (const float*)d_in[4];
    const float* bhh   = (const float*)d_in[5];
    const float* fc1w  = (const float*)d_in[6];
    const float* fc1b  = (const float*)d_in[7];
    const float* fc2w  = (const float*)d_in[8];
    const float* fc2b  = (const float*)d_in[9];
    float* out = (float*)d_out;

    char* ws = (char*)d_ws;
    unsigned short* Wihb   = (unsigned short*)(ws + WS_WIHB);
    unsigned short* WhhImg = (unsigned short*)(ws + WS_WHH);
    float*          bsum   = (float*)(ws + WS_BSUM);
    unsigned short* hA     = (unsigned short*)(ws + WS_HA);
    unsigned short* hB     = (unsigned short*)(ws + WS_HB);
    float*          cbuf   = (float*)(ws + WS_C);
    float*          feat   = (float*)(ws + WS_FEAT);
    float*          z1     = (float*)(ws + WS_Z1);
    unsigned short* Xg     = (unsigned short*)(ws + WS_XG);

    prep_w<<<dim3((PREPW_TOTAL + 255) / 256), dim3(256), 0, stream>>>(
        Wih_f, Whh_f, bih, bhh, Wihb, WhhImg, bsum, hA, cbuf);

    xg_gemm<<<dim3(4096), dim3(256), 0, stream>>>(xf, xa, Wihb, Xg);

    for (int t = 0; t < Ln; ++t) {
        const unsigned short* hin = (t & 1) ? hB : hA;
        unsigned short* hout      = (t & 1) ? hA : hB;
        lstm_step<<<dim3(512), dim3(256), 0, stream>>>(
            WhhImg, Xg, bsum, hin, hout, cbuf, t);
    }
    // t=63 wrote hA
    pool_kernel<<<dim3(32), dim3(256), 0, stream>>>(hA, feat);
    fc1_kernel<<<dim3(256), dim3(256), 0, stream>>>(feat, fc1w, fc1b, z1);
    fc2_kernel<<<dim3(16), dim3(256), 0, stream>>>(z1, fc2w, fc2b, out);
}